// Round 1
// baseline (111.189 us; speedup 1.0000x reference)
//
#include <hip/hip_runtime.h>

#define NODES 128
#define FEAT  32
#define XPAD  136   // XT row stride (bf16 elems): 272B rows -> conflict-free B-frag ds_read_b128

typedef __attribute__((ext_vector_type(8))) short bf16x8;
typedef __attribute__((ext_vector_type(4))) float f32x4;

// RNE fp32->bf16 pack of two floats into one dword (lo = a, hi = b)
__device__ __forceinline__ unsigned pk_bf16(float a, float b) {
    unsigned ua = __builtin_bit_cast(unsigned, a);
    unsigned ub = __builtin_bit_cast(unsigned, b);
    ua += 0x7fffu + ((ua >> 16) & 1u);
    ub += 0x7fffu + ((ub >> 16) & 1u);
    return (ua >> 16) | (ub & 0xffff0000u);
}

__device__ __forceinline__ bf16x8 cvt_frag(float4 lo, float4 hi) {
    union { unsigned u[4]; bf16x8 v; } r;
    r.u[0] = pk_bf16(lo.x, lo.y);
    r.u[1] = pk_bf16(lo.z, lo.w);
    r.u[2] = pk_bf16(hi.x, hi.y);
    r.u[3] = pk_bf16(hi.z, hi.w);
    return r.v;
}

// One 512-thread block (8 waves) per batch element; wave w owns output rows
// 16w..16w+15.
//
// KEY CHANGE vs previous version: W rows are PARTITIONED across waves (wave w
// only reads rows 16w..16w+15) -- zero cross-wave reuse -- so LDS staging of W
// was pure overhead (32KB LDS + 2 extra barriers + rotation math). Each lane
// now loads its exact MFMA A-fragment straight from global: lane (w,ln,q)
// needs W[16w+ln][kb*32+q*8 .. +7] = two dwordx4 per k-tile, 8 loads issued
// up-front (8-deep MLP/wave, 128B-contiguous segments per row).
//
// X keeps the LDS transpose (8x cross-wave reuse). The single barrier is a raw
// s_barrier with manual lgkmcnt(0): only the xt ds_writes drain; the 8 W
// global loads stay IN FLIGHT across the barrier, and each wave's first MFMA
// waits only on its own kb0 pair (compiler-tracked vmcnt), overlapping the
// rest of the W stream with compute.
//
// LDS 8.5 KB (was 40.5) -> blocks/CU bounded by waves only; VGPR ~70 ->
// __launch_bounds__(512,6) = 3 blocks/CU, 24 waves/CU.
__global__ __launch_bounds__(512, 6)
void blockdiag_mm(const float* __restrict__ inp,
                  const float* __restrict__ weights,
                  const int* __restrict__ idx,
                  float* __restrict__ out)
{
    __shared__ __align__(16) short xt[FEAT * XPAD];  // 8.5 KiB: XT[f][k] bf16

    const int b  = blockIdx.x;
    const int u  = threadIdx.x;   // 0..511
    const int w  = u >> 6;        // wave 0..7
    const int l  = u & 63;
    const int ln = l & 15;        // A row within 16-tile / D col lane
    const int q  = l >> 4;        // k-quad 0..3

    const float* __restrict__ xin = inp + (size_t)b * (NODES * FEAT);
    const float* __restrict__ wb  = weights + (size_t)idx[b] * (NODES * NODES);

    // ---- X global loads first (independent of the idx scalar-load latency)
    const float4* x4 = (const float4*)xin;
    const int fq = u & 7;            // feature quad
    const int k0 = (u >> 3) * 2;     // 0,2,...,126
    const float4 v0 = x4[k0 * 8 + fq];
    const float4 v1 = x4[(k0 + 1) * 8 + fq];

    // ---- W direct-to-register loads: A-fragment exactly as MFMA wants it.
    // float4 index: (row)*32 + kb*8 + q*2 (+1)  ==  floats row*128 + kb*32 + q*8
    const float4* w4 = (const float4*)wb;
    const int wbase = (16 * w + ln) * 32 + q * 2;
    float4 wf[8];
    #pragma unroll
    for (int kb = 0; kb < 4; ++kb) {
        wf[2 * kb + 0] = w4[wbase + kb * 8 + 0];
        wf[2 * kb + 1] = w4[wbase + kb * 8 + 1];
    }

    // ---- transpose-pack X into xt (bf16) while W loads fly
    {
        const float pv0[4] = {v0.x, v0.y, v0.z, v0.w};
        const float pv1[4] = {v1.x, v1.y, v1.z, v1.w};
        #pragma unroll
        for (int i = 0; i < 4; ++i)
            *(unsigned*)(&xt[(fq * 4 + i) * XPAD + k0]) = pk_bf16(pv0[i], pv1[i]);
    }

    // ---- raw barrier: drain ONLY the LDS writes (lgkmcnt); W global loads
    // (vmcnt) stay in flight across the barrier. __syncthreads() would emit
    // s_waitcnt vmcnt(0) and serialize the whole W stream before any MFMA.
    __builtin_amdgcn_sched_barrier(0);
    asm volatile("s_waitcnt lgkmcnt(0)" ::: "memory");
    __builtin_amdgcn_s_barrier();
    __builtin_amdgcn_sched_barrier(0);

    f32x4 acc[2] = {};
    #pragma unroll
    for (int kb = 0; kb < 4; ++kb) {
        const bf16x8 afr = cvt_frag(wf[2 * kb + 0], wf[2 * kb + 1]);
        #pragma unroll
        for (int nt = 0; nt < 2; ++nt) {
            const bf16x8 bfr = *(const bf16x8*)(&xt[(16 * nt + ln) * XPAD + kb * 32 + q * 8]);
            acc[nt] = __builtin_amdgcn_mfma_f32_16x16x32_bf16(afr, bfr, acc[nt], 0, 0, 0);
        }
    }

    // ---- store: D layout col=lane&15, row=(lane>>4)*4+reg (m89-verified)
    float* ob = out + (size_t)b * (NODES * FEAT);
    #pragma unroll
    for (int nt = 0; nt < 2; ++nt)
        #pragma unroll
        for (int reg = 0; reg < 4; ++reg)
            ob[(16 * w + q * 4 + reg) * FEAT + 16 * nt + ln] = acc[nt][reg];
}

extern "C" void kernel_launch(void* const* d_in, const int* in_sizes, int n_in,
                              void* d_out, int out_size, void* d_ws, size_t ws_size,
                              hipStream_t stream) {
    const float* inp = (const float*)d_in[0];
    const float* wts = (const float*)d_in[1];
    const int*   idx = (const int*)d_in[2];
    float* outp = (float*)d_out;
    const int B = in_sizes[2];   // 1024
    hipLaunchKernelGGL(blockdiag_mm, dim3(B), dim3(512), 0, stream,
                       inp, wts, idx, outp);
}

// Round 2
// 109.853 us; speedup vs baseline: 1.0122x; 1.0122x over previous
//
#include <hip/hip_runtime.h>

#define NODES 128
#define FEAT  32
#define XPAD  136   // XT row stride (bf16 elems): 272B rows -> conflict-free B-frag ds_read_b128

typedef __attribute__((ext_vector_type(8))) short bf16x8;
typedef __attribute__((ext_vector_type(4))) float f32x4;

// RNE fp32->bf16 pack of two floats into one dword (lo = a, hi = b)
__device__ __forceinline__ unsigned pk_bf16(float a, float b) {
    unsigned ua = __builtin_bit_cast(unsigned, a);
    unsigned ub = __builtin_bit_cast(unsigned, b);
    ua += 0x7fffu + ((ua >> 16) & 1u);
    ub += 0x7fffu + ((ub >> 16) & 1u);
    return (ua >> 16) | (ub & 0xffff0000u);
}

__device__ __forceinline__ bf16x8 cvt_frag(float4 lo, float4 hi) {
    union { unsigned u[4]; bf16x8 v; } r;
    r.u[0] = pk_bf16(lo.x, lo.y);
    r.u[1] = pk_bf16(lo.z, lo.w);
    r.u[2] = pk_bf16(hi.x, hi.y);
    r.u[3] = pk_bf16(hi.z, hi.w);
    return r.v;
}

// R2: 512 blocks, each handling TWO batch elements (2b, 2b+1).
//
// R1 post-mortem: removing W's LDS staging was neutral -> the kernel is not
// bound by intra-block staging/barriers (TLP across 3 resident blocks already
// hid them). Remaining gap to the 16us traffic floor is BLOCK-BOUNDARY
// serialization: 1024 blocks = 4 scheduling generations per CU, and each new
// block pays idx-load -> address -> issue before its 64KB W stream starts, so
// the CU's load pipe has gaps.
//
// Fix: grid 512 = 2 blocks/CU, ALL co-resident (launch_bounds(512,4), VGPR
// ~110 < 128). Each lane issues all 20 VMEM loads (4 X + 16 W across both
// elements) in the prologue: the CU's entire 384KB demand is in flight from
// t~0, one uninterrupted stream, no generations, no tail, idx latency paid
// once. compute0 waits only on wf[0] regs (counted vmcnt; wf[1] stays in
// flight); single lgkm-only barrier covers both xt buffers.
__global__ __launch_bounds__(512, 4)
void blockdiag_mm(const float* __restrict__ inp,
                  const float* __restrict__ weights,
                  const int* __restrict__ idx,
                  float* __restrict__ out,
                  int B)
{
    __shared__ __align__(16) short xt[2][FEAT * XPAD];  // 17 KiB: XT[f][k] bf16, per element

    const int b0 = 2 * blockIdx.x;
    const int b1 = b0 + 1;
    const bool b1ok = (b1 < B);

    const int u  = threadIdx.x;   // 0..511
    const int w  = u >> 6;        // wave 0..7
    const int l  = u & 63;
    const int ln = l & 15;        // A row within 16-tile / D col lane
    const int q  = l >> 4;        // k-quad 0..3

    const int i0 = idx[b0];
    const int i1 = b1ok ? idx[b1] : i0;

    // ---- X global loads first (independent of the idx scalar-load latency)
    const float4* x40 = (const float4*)(inp + (size_t)b0 * (NODES * FEAT));
    const float4* x41 = x40 + (NODES * FEAT / 4);
    const int fq = u & 7;            // feature quad
    const int k0 = (u >> 3) * 2;     // 0,2,...,126
    float4 xv[4];
    xv[0] = x40[k0 * 8 + fq];
    xv[1] = x40[(k0 + 1) * 8 + fq];
    xv[2] = x41[k0 * 8 + fq];
    xv[3] = x41[(k0 + 1) * 8 + fq];

    // ---- W direct-to-register loads for BOTH elements, issued back-to-back.
    // Lane (w,ln,q) needs W[16w+ln][kb*32+q*8 .. +7]: 2 dwordx4 per k-tile.
    const float4* w4e[2] = {
        (const float4*)(weights + (size_t)i0 * (NODES * NODES)),
        (const float4*)(weights + (size_t)i1 * (NODES * NODES))
    };
    const int wbase = (16 * w + ln) * 32 + q * 2;
    float4 wf[2][8];
    #pragma unroll
    for (int e = 0; e < 2; ++e)
        #pragma unroll
        for (int kb = 0; kb < 4; ++kb) {
            wf[e][2 * kb + 0] = w4e[e][wbase + kb * 8 + 0];
            wf[e][2 * kb + 1] = w4e[e][wbase + kb * 8 + 1];
        }

    // ---- transpose-pack both X slabs into xt (bf16) while W loads fly
    #pragma unroll
    for (int e = 0; e < 2; ++e) {
        const float pv0[4] = {xv[2*e].x, xv[2*e].y, xv[2*e].z, xv[2*e].w};
        const float pv1[4] = {xv[2*e+1].x, xv[2*e+1].y, xv[2*e+1].z, xv[2*e+1].w};
        #pragma unroll
        for (int i = 0; i < 4; ++i)
            *(unsigned*)(&xt[e][(fq * 4 + i) * XPAD + k0]) = pk_bf16(pv0[i], pv1[i]);
    }

    // ---- raw barrier: drain ONLY the LDS writes (lgkmcnt); all 16 W global
    // loads (vmcnt) stay in flight across it.
    __builtin_amdgcn_sched_barrier(0);
    asm volatile("s_waitcnt lgkmcnt(0)" ::: "memory");
    __builtin_amdgcn_s_barrier();
    __builtin_amdgcn_sched_barrier(0);

    #pragma unroll
    for (int e = 0; e < 2; ++e) {
        f32x4 acc[2] = {};
        #pragma unroll
        for (int kb = 0; kb < 4; ++kb) {
            const bf16x8 afr = cvt_frag(wf[e][2 * kb + 0], wf[e][2 * kb + 1]);
            #pragma unroll
            for (int nt = 0; nt < 2; ++nt) {
                const bf16x8 bfr = *(const bf16x8*)(&xt[e][(16 * nt + ln) * XPAD + kb * 32 + q * 8]);
                acc[nt] = __builtin_amdgcn_mfma_f32_16x16x32_bf16(afr, bfr, acc[nt], 0, 0, 0);
            }
        }
        // ---- store: D layout col=lane&15, row=(lane>>4)*4+reg (m89-verified)
        if (e == 0 || b1ok) {
            float* ob = out + (size_t)(b0 + e) * (NODES * FEAT);
            #pragma unroll
            for (int nt = 0; nt < 2; ++nt)
                #pragma unroll
                for (int reg = 0; reg < 4; ++reg)
                    ob[(16 * w + q * 4 + reg) * FEAT + 16 * nt + ln] = acc[nt][reg];
        }
    }
}

extern "C" void kernel_launch(void* const* d_in, const int* in_sizes, int n_in,
                              void* d_out, int out_size, void* d_ws, size_t ws_size,
                              hipStream_t stream) {
    const float* inp = (const float*)d_in[0];
    const float* wts = (const float*)d_in[1];
    const int*   idx = (const int*)d_in[2];
    float* outp = (float*)d_out;
    const int B = in_sizes[2];   // 1024
    hipLaunchKernelGGL(blockdiag_mm, dim3((B + 1) / 2), dim3(512), 0, stream,
                       inp, wts, idx, outp, B);
}